// Round 10
// baseline (435.242 us; speedup 1.0000x reference)
//
#include <hip/hip_runtime.h>
#include <hip/hip_bf16.h>

#define HF 64
#define EPS 1e-5f

#define BSH 9                    // bucket shift: 512 nodes / bucket
#define BKN (1 << BSH)           // 512 nodes per bucket
#define NBUCK_MAX 256            // >= ceil(N / BKN); also >= blockDim of scan kernels
#define PB_T 256                 // passB threads
#define PB_EPT 32                // edges per thread
#define PB_TILE (PB_T * PB_EPT)  // 8192 edges per block

#define LGRID 3072               // k_layer grid: grid-stride over nodes (tail fill)

typedef __hip_bfloat16 bf16;
typedef __fp16 f16x2 __attribute__((ext_vector_type(2)));   // matches cvt_pkrtz return type

#if __has_builtin(__builtin_amdgcn_fdot2) && __has_builtin(__builtin_amdgcn_cvt_pkrtz)
#define USE_FDOT2 1
#else
#define USE_FDOT2 0
#endif

__device__ __forceinline__ unsigned char f32_to_fp8(float v) {
    int p = __builtin_amdgcn_cvt_pk_fp8_f32(v, v, 0, false);
    return (unsigned char)(p & 0xff);
}

__device__ __forceinline__ float rdlane(float v, int k) {
    return __int_as_float(__builtin_amdgcn_readlane(__float_as_int(v), k));
}

__device__ __forceinline__ unsigned bf16_rne_hi(float x) {
    unsigned u = __float_as_uint(x);
    return (u + 0x7fffu + ((u >> 16) & 1u)) & 0xffff0000u;  // rounded, kept in high half
}

#if USE_FDOT2
__device__ __forceinline__ unsigned pack_f16(float a, float b) {
    f16x2 h = __builtin_amdgcn_cvt_pkrtz(a, b);
    union { f16x2 h; unsigned u; } c; c.h = h; return c.u;
}
__device__ __forceinline__ f16x2 as_f16x2(unsigned u) {
    union { unsigned u; f16x2 h; } c; c.u = u; return c.h;
}
#endif

// ---- pass B2: bin each tile IN PLACE (block-local bucket sort) + run table ----
// stage[tile0..tile0+cnt) = tile's edges grouped by bucket; rtab[blk*B+b] = off<<14|cnt.
// Also accumulates global bucket totals bcnt via one atomic per (block,bucket).
__global__ __launch_bounds__(PB_T) void k_passB2(
    const int* __restrict__ src, const int* __restrict__ dst,
    int* __restrict__ stage, unsigned* __restrict__ rtab,
    int* __restrict__ bcnt, int E, int B) {
    __shared__ int scnt[NBUCK_MAX];
    __shared__ int sscan[PB_T];
    int t = threadIdx.x;
    int blk = blockIdx.x;
    int tile0 = blk * PB_TILE;

    for (int b = t; b < NBUCK_MAX; b += PB_T) scnt[b] = 0;
    __syncthreads();

    int rec[PB_EPT];
    int bkt[PB_EPT];
#pragma unroll
    for (int k = 0; k < PB_EPT; ++k) {
        int e = tile0 + k * PB_T + t;
        bkt[k] = -1;
        if (e < E) {
            int d = dst[e];
            int s = src[e];
            int b = d >> BSH;
            bkt[k] = b;
            rec[k] = s | ((d & (BKN - 1)) << 17);
            atomicAdd(&scnt[b], 1);
        }
    }
    __syncthreads();

    // exclusive scan of per-bucket counts (256-wide Hillis-Steele)
    int v = (t < B) ? scnt[t] : 0;
    sscan[t] = v;
    __syncthreads();
    for (int off = 1; off < PB_T; off <<= 1) {
        int val = sscan[t];
        int add = (t >= off) ? sscan[t - off] : 0;
        __syncthreads();
        sscan[t] = val + add;
        __syncthreads();
    }
    int excl = sscan[t] - v;
    if (t < B) {
        rtab[(size_t)blk * B + t] = ((unsigned)excl << 14) | (unsigned)v;
        scnt[t] = excl;     // reuse as write cursor
        if (v) atomicAdd(&bcnt[t], v);   // global bucket totals (cheap: 196 addrs)
    }
    __syncthreads();

#pragma unroll
    for (int k = 0; k < PB_EPT; ++k) {
        if (bkt[k] >= 0) {
            int loc = atomicAdd(&scnt[bkt[k]], 1);
            stage[tile0 + loc] = rec[k];   // block-private: stays in a 32KB window
        }
    }
}

// ---- bscan3: PARALLEL exclusive scan of bcnt (1 block, LDS Hillis-Steele) ----
__global__ void k_bscan3(const int* __restrict__ bcnt, int* __restrict__ bbase2,
                         int* __restrict__ base, int B, int N, int E) {
    __shared__ int tot[NBUCK_MAX];
    int t = threadIdx.x;   // blockDim == 256
    int v = (t < B) ? bcnt[t] : 0;
    tot[t] = v;
    __syncthreads();
    for (int off = 1; off < 256; off <<= 1) {
        int val = tot[t];
        int add = (t >= off) ? tot[t - off] : 0;
        __syncthreads();
        tot[t] = val + add;
        __syncthreads();
    }
    if (t < B) bbase2[t] = tot[t] - v;
    if (t == 0) { bbase2[B] = E; base[N] = E; }
}

// ---- pass C2: per bucket: walk runs -> LDS hist -> scan -> base/dinv -> scatter ----
__global__ __launch_bounds__(512) void k_passC2(const int* __restrict__ stage,
                                                const unsigned* __restrict__ rtab,
                                                const int* __restrict__ bb2,
                                                int* __restrict__ base,
                                                float* __restrict__ dinv,
                                                int* __restrict__ csr,
                                                int N, int B, int nblk) {
    __shared__ int lcnt[BKN];
    __shared__ int lscan[BKN];
    __shared__ int lcur[BKN];
    int beta = blockIdx.x;
    int n0 = beta * BKN;
    int n1 = n0 + BKN; if (n1 > N) n1 = N;
    int nn = n1 - n0;
    int t = threadIdx.x;       // blockDim == 512 == BKN
    int rg = t >> 4;           // run group 0..31 (32 runs in parallel)
    int le = t & 15;           // lane within run group
    lcnt[t] = 0;
    __syncthreads();

    // phase 1: histogram over this bucket's runs
    for (int blk0 = 0; blk0 < nblk; blk0 += 32) {
        int blk = blk0 + rg;
        if (blk < nblk) {
            unsigned rt = rtab[(size_t)blk * B + beta];
            int cnt = (int)(rt & 0x3FFFu);
            int off = blk * PB_TILE + (int)(rt >> 14);
            for (int i = le; i < cnt; i += 16)
                atomicAdd(&lcnt[stage[off + i] >> 17], 1);
        }
    }
    __syncthreads();
    int v = lcnt[t];
    lscan[t] = v;
    __syncthreads();
    for (int off = 1; off < 512; off <<= 1) {
        int val = lscan[t];
        int add = (t >= off) ? lscan[t - off] : 0;
        __syncthreads();
        lscan[t] = val + add;
        __syncthreads();
    }
    int b = bb2[beta] + lscan[t] - v;   // exclusive scan + bucket start
    if (t < nn) {
        base[n0 + t] = b;
        dinv[n0 + t] = rsqrtf((float)v + 1.0f);
    }
    lcur[t] = b;
    __syncthreads();

    // phase 2: scatter to csr
    for (int blk0 = 0; blk0 < nblk; blk0 += 32) {
        int blk = blk0 + rg;
        if (blk < nblk) {
            unsigned rt = rtab[(size_t)blk * B + beta];
            int cnt = (int)(rt & 0x3FFFu);
            int off = blk * PB_TILE + (int)(rt >> 14);
            for (int i = le; i < cnt; i += 16) {
                int r = stage[off + i];
                int pos = atomicAdd(&lcur[r >> 17], 1);
                csr[pos] = r & 0x1ffff;
            }
        }
    }
}

// ---- prescale: xs[n,c] = x[n,c] * dinv[n] ----
__global__ void k_prescale(const float* __restrict__ x, const float* __restrict__ dinv,
                           float* __restrict__ xs, int N5) {
    int i = blockIdx.x * blockDim.x + threadIdx.x;
    if (i < N5) xs[i] = x[i] * dinv[i / 5];
}

// ---- layer 1 fused: pipelined multi-neighbor gather (8 nbr / VMEM instr) ----
__global__ __launch_bounds__(256) void k_layer1(
    const float* __restrict__ xs, unsigned char* __restrict__ hout,
    const int* __restrict__ csr, const int* __restrict__ basep,
    const float* __restrict__ dinv,
    const float* __restrict__ W1, const float* __restrict__ b,
    const float* __restrict__ g, const float* __restrict__ be,
    const float* __restrict__ rm, const float* __restrict__ rv, int N) {
    __shared__ float sW[5 * HF];
    __shared__ float sB[HF];
    __shared__ float sScale[HF];
    if (threadIdx.x < HF) {
        int f = threadIdx.x;
        float scale = g[f] * rsqrtf(rv[f] + EPS);
        sScale[f] = scale;
        sB[f] = (b[f] - rm[f]) * scale + be[f];
    }
    __syncthreads();
    for (int i = threadIdx.x; i < 5 * HF; i += blockDim.x)
        sW[i] = W1[i] * sScale[i & (HF - 1)];
    __syncthreads();

    int lane = threadIdx.x & 63;
    int wave = threadIdx.x >> 6;
    int c  = lane & 7;     // feature (c<5 useful)
    int g8 = lane >> 3;    // neighbor slot 0..7
    int stride = gridDim.x * 4;

    auto mlp_store = [&](float accS, int nodeS, float diS) {
        float out = sB[lane];
#pragma unroll
        for (int k = 0; k < 5; ++k) out += __shfl(accS, k, 64) * sW[k * HF + lane];
        out = fmaxf(out, 0.f);
        hout[(size_t)nodeS * HF + lane] = f32_to_fp8(out * diS);
    };

    float accP = 0.f, diP = 0.f;
    int nodeP = -1;

    for (int node = blockIdx.x * 4 + wave; node < N; node += stride) {
        int j   = __builtin_amdgcn_readfirstlane(basep[node]);
        int end = __builtin_amdgcn_readfirstlane(basep[node + 1]);

        float a0 = 0.f, a1 = 0.f, a2 = 0.f, a3 = 0.f;
        if (g8 == 0 && c < 5) a0 = xs[node * 5 + c];   // self term, issued early

        // issue first 32-window before prev node's MLP
        float u0 = 0.f, u1 = 0.f, u2 = 0.f, u3 = 0.f;
        bool w0 = (j + 32 <= end);
        if (w0) {
            int s0 = csr[j + g8];
            int s1 = csr[j + 8 + g8];
            int s2 = csr[j + 16 + g8];
            int s3 = csr[j + 24 + g8];
            u0 = xs[s0 * 5 + c]; u1 = xs[s1 * 5 + c];
            u2 = xs[s2 * 5 + c]; u3 = xs[s3 * 5 + c];
        }

        if (nodeP >= 0) mlp_store(accP, nodeP, diP);   // LDS/VALU only

        if (w0) {
            j += 32;
            while (j + 32 <= end) {   // double-buffered: issue next, consume current
                int s0 = csr[j + g8];
                int s1 = csr[j + 8 + g8];
                int s2 = csr[j + 16 + g8];
                int s3 = csr[j + 24 + g8];
                float v0 = xs[s0 * 5 + c];
                float v1 = xs[s1 * 5 + c];
                float v2 = xs[s2 * 5 + c];
                float v3 = xs[s3 * 5 + c];
                a0 += u0; a1 += u1; a2 += u2; a3 += u3;
                u0 = v0; u1 = v1; u2 = v2; u3 = v3;
                j += 32;
            }
            a0 += u0; a1 += u1; a2 += u2; a3 += u3;
        }
        for (; j + 8 <= end; j += 8) {
            int s = csr[j + g8];
            a0 += xs[s * 5 + c];
        }
        if (j < end && j + g8 < end) {
            int s = csr[j + g8];
            a0 += xs[s * 5 + c];
        }

        // fold the 8 neighbor slots
        float acc = (a0 + a1) + (a2 + a3);
        acc += __shfl_xor(acc, 8, 64);
        acc += __shfl_xor(acc, 16, 64);
        acc += __shfl_xor(acc, 32, 64);

        float di = dinv[node];
        accP = acc * di;
        diP = di;
        nodeP = node;
    }
    if (nodeP >= 0) mlp_store(accP, nodeP, diP);
}

// ---- layers 2/3: 16-wide double-buffered byte-gather + LDS f16 weights + fdot2 MLP ----
// MLP: v_dot2_f32_f16 (2 MACs/instr, f32 accum) on packed f16 weight pairs cuts
// the 192-op readlane/unpack/FMA chain to ~128 ops/node. Gather: 16 loads in
// flight double-buffered (VGPR 28 -> ~70, still far under the 128 cap: no spill).
// SCALE_OUT=1: write fp8 hs=h*dinv. SCALE_OUT=0: write bf16 h (feeds pool).
template <int SCALE_OUT>
__global__ __launch_bounds__(256, 4) void k_layer(
    const unsigned char* __restrict__ hs8, void* __restrict__ hout_v,
    const int* __restrict__ csr, const int* __restrict__ basep,
    const float* __restrict__ dinv,
    const float* __restrict__ W, const float* __restrict__ b,
    const float* __restrict__ g, const float* __restrict__ be,
    const float* __restrict__ rm, const float* __restrict__ rv, int N) {
    __shared__ uint4 swp4[64][9];   // padded row: 144B stride, conflict-free reads

    int lane = threadIdx.x & 63;
    int wave = threadIdx.x >> 6;
    int stride = gridDim.x * 4;
    const unsigned char* col = hs8 + lane;   // lane's feature column

    // stage BN-folded weight columns once per block (f16 pairs if fdot2 available)
    if (threadIdx.x < 64) {
        int l = threadIdx.x;
        float sc = g[l] * rsqrtf(rv[l] + EPS);
#pragma unroll
        for (int c = 0; c < 8; ++c) {
            unsigned p[4];
#pragma unroll
            for (int q = 0; q < 4; ++q) {
                int k2 = c * 4 + q;
                float w0 = W[(2 * k2 + 0) * HF + l] * sc;
                float w1 = W[(2 * k2 + 1) * HF + l] * sc;
#if USE_FDOT2
                p[q] = pack_f16(w0, w1);
#else
                p[q] = (bf16_rne_hi(w0) >> 16) | bf16_rne_hi(w1);
#endif
            }
            swp4[l][c] = make_uint4(p[0], p[1], p[2], p[3]);
        }
    }
    __syncthreads();

    float scale = g[lane] * rsqrtf(rv[lane] + EPS);
    float bias  = (b[lane] - rm[lane]) * scale + be[lane];

    auto mlp_store = [&](float acc, int nodeS, float diS) {
        float o0 = bias, o1 = 0.f, o2 = 0.f, o3 = 0.f;
#pragma unroll
        for (int c = 0; c < 8; ++c) {
            uint4 pv = swp4[lane][c];
            int k0 = c * 8;
#if USE_FDOT2
            f16x2 a01 = __builtin_amdgcn_cvt_pkrtz(rdlane(acc, k0 + 0), rdlane(acc, k0 + 1));
            f16x2 a23 = __builtin_amdgcn_cvt_pkrtz(rdlane(acc, k0 + 2), rdlane(acc, k0 + 3));
            f16x2 a45 = __builtin_amdgcn_cvt_pkrtz(rdlane(acc, k0 + 4), rdlane(acc, k0 + 5));
            f16x2 a67 = __builtin_amdgcn_cvt_pkrtz(rdlane(acc, k0 + 6), rdlane(acc, k0 + 7));
            o0 = __builtin_amdgcn_fdot2(a01, as_f16x2(pv.x), o0, false);
            o1 = __builtin_amdgcn_fdot2(a23, as_f16x2(pv.y), o1, false);
            o2 = __builtin_amdgcn_fdot2(a45, as_f16x2(pv.z), o2, false);
            o3 = __builtin_amdgcn_fdot2(a67, as_f16x2(pv.w), o3, false);
#else
            o0 += rdlane(acc, k0 + 0) * __uint_as_float(pv.x << 16);
            o1 += rdlane(acc, k0 + 1) * __uint_as_float(pv.x & 0xffff0000u);
            o0 += rdlane(acc, k0 + 2) * __uint_as_float(pv.y << 16);
            o1 += rdlane(acc, k0 + 3) * __uint_as_float(pv.y & 0xffff0000u);
            o2 += rdlane(acc, k0 + 4) * __uint_as_float(pv.z << 16);
            o3 += rdlane(acc, k0 + 5) * __uint_as_float(pv.z & 0xffff0000u);
            o2 += rdlane(acc, k0 + 6) * __uint_as_float(pv.w << 16);
            o3 += rdlane(acc, k0 + 7) * __uint_as_float(pv.w & 0xffff0000u);
#endif
        }
        float out = fmaxf((o0 + o1) + (o2 + o3), 0.f);
        if (SCALE_OUT) {
            ((unsigned char*)hout_v)[(size_t)nodeS * HF + lane] = f32_to_fp8(out * diS);
        } else {
            ((unsigned short*)hout_v)[(size_t)nodeS * HF + lane] =
                (unsigned short)(bf16_rne_hi(out) >> 16);
        }
    };

    float accP = 0.f, diP = 0.f;
    int nodeP = -1;

    for (int node = blockIdx.x * 4 + wave; node < N; node += stride) {
        int j   = __builtin_amdgcn_readfirstlane(basep[node]);
        int end = __builtin_amdgcn_readfirstlane(basep[node + 1]);

        // self term (already *dinv[src])
        float a0 = __builtin_amdgcn_cvt_f32_fp8((unsigned)col[(size_t)node * HF], 0);
        float a1 = 0.f, a2 = 0.f, a3 = 0.f;

        // issue first 16-window BEFORE prev node's MLP -> loads fly under the MLP
        unsigned u0 = 0, u1 = 0, u2 = 0, u3 = 0, u4 = 0, u5 = 0, u6 = 0, u7 = 0;
        unsigned u8 = 0, u9 = 0, uA = 0, uB = 0, uC = 0, uD = 0, uE = 0, uF = 0;
        bool w0 = (j + 16 <= end);
        if (w0) {
            int s0 = csr[j+0],  s1 = csr[j+1],  s2 = csr[j+2],  s3 = csr[j+3];
            int s4 = csr[j+4],  s5 = csr[j+5],  s6 = csr[j+6],  s7 = csr[j+7];
            int s8 = csr[j+8],  s9 = csr[j+9],  sA = csr[j+10], sB_ = csr[j+11];
            int sC = csr[j+12], sD = csr[j+13], sE = csr[j+14], sF = csr[j+15];
            u0 = col[(size_t)s0 * HF]; u1 = col[(size_t)s1 * HF];
            u2 = col[(size_t)s2 * HF]; u3 = col[(size_t)s3 * HF];
            u4 = col[(size_t)s4 * HF]; u5 = col[(size_t)s5 * HF];
            u6 = col[(size_t)s6 * HF]; u7 = col[(size_t)s7 * HF];
            u8 = col[(size_t)s8 * HF]; u9 = col[(size_t)s9 * HF];
            uA = col[(size_t)sA * HF]; uB = col[(size_t)sB_ * HF];
            uC = col[(size_t)sC * HF]; uD = col[(size_t)sD * HF];
            uE = col[(size_t)sE * HF]; uF = col[(size_t)sF * HF];
        }

        // previous node's MLP + store (vmcnt-free: LDS + readlane + VALU only)
        if (nodeP >= 0) mlp_store(accP, nodeP, diP);

        if (w0) {
            j += 16;
            // steady state: issue next 16 while consuming current 16 (counted vmcnt)
            while (j + 16 <= end) {
                int t0 = csr[j+0],  t1 = csr[j+1],  t2 = csr[j+2],  t3 = csr[j+3];
                int t4 = csr[j+4],  t5 = csr[j+5],  t6 = csr[j+6],  t7 = csr[j+7];
                int t8 = csr[j+8],  t9 = csr[j+9],  tA = csr[j+10], tB = csr[j+11];
                int tC = csr[j+12], tD = csr[j+13], tE = csr[j+14], tF = csr[j+15];
                unsigned v0 = col[(size_t)t0 * HF], v1 = col[(size_t)t1 * HF];
                unsigned v2 = col[(size_t)t2 * HF], v3 = col[(size_t)t3 * HF];
                unsigned v4 = col[(size_t)t4 * HF], v5 = col[(size_t)t5 * HF];
                unsigned v6 = col[(size_t)t6 * HF], v7 = col[(size_t)t7 * HF];
                unsigned v8 = col[(size_t)t8 * HF], v9 = col[(size_t)t9 * HF];
                unsigned vA = col[(size_t)tA * HF], vB = col[(size_t)tB * HF];
                unsigned vC = col[(size_t)tC * HF], vD = col[(size_t)tD * HF];
                unsigned vE = col[(size_t)tE * HF], vF = col[(size_t)tF * HF];
                a0 += __builtin_amdgcn_cvt_f32_fp8(u0, 0);
                a1 += __builtin_amdgcn_cvt_f32_fp8(u1, 0);
                a2 += __builtin_amdgcn_cvt_f32_fp8(u2, 0);
                a3 += __builtin_amdgcn_cvt_f32_fp8(u3, 0);
                a0 += __builtin_amdgcn_cvt_f32_fp8(u4, 0);
                a1 += __builtin_amdgcn_cvt_f32_fp8(u5, 0);
                a2 += __builtin_amdgcn_cvt_f32_fp8(u6, 0);
                a3 += __builtin_amdgcn_cvt_f32_fp8(u7, 0);
                a0 += __builtin_amdgcn_cvt_f32_fp8(u8, 0);
                a1 += __builtin_amdgcn_cvt_f32_fp8(u9, 0);
                a2 += __builtin_amdgcn_cvt_f32_fp8(uA, 0);
                a3 += __builtin_amdgcn_cvt_f32_fp8(uB, 0);
                a0 += __builtin_amdgcn_cvt_f32_fp8(uC, 0);
                a1 += __builtin_amdgcn_cvt_f32_fp8(uD, 0);
                a2 += __builtin_amdgcn_cvt_f32_fp8(uE, 0);
                a3 += __builtin_amdgcn_cvt_f32_fp8(uF, 0);
                u0 = v0; u1 = v1; u2 = v2; u3 = v3;
                u4 = v4; u5 = v5; u6 = v6; u7 = v7;
                u8 = v8; u9 = v9; uA = vA; uB = vB;
                uC = vC; uD = vD; uE = vE; uF = vF;
                j += 16;
            }
            // drain final window
            a0 += __builtin_amdgcn_cvt_f32_fp8(u0, 0);
            a1 += __builtin_amdgcn_cvt_f32_fp8(u1, 0);
            a2 += __builtin_amdgcn_cvt_f32_fp8(u2, 0);
            a3 += __builtin_amdgcn_cvt_f32_fp8(u3, 0);
            a0 += __builtin_amdgcn_cvt_f32_fp8(u4, 0);
            a1 += __builtin_amdgcn_cvt_f32_fp8(u5, 0);
            a2 += __builtin_amdgcn_cvt_f32_fp8(u6, 0);
            a3 += __builtin_amdgcn_cvt_f32_fp8(u7, 0);
            a0 += __builtin_amdgcn_cvt_f32_fp8(u8, 0);
            a1 += __builtin_amdgcn_cvt_f32_fp8(u9, 0);
            a2 += __builtin_amdgcn_cvt_f32_fp8(uA, 0);
            a3 += __builtin_amdgcn_cvt_f32_fp8(uB, 0);
            a0 += __builtin_amdgcn_cvt_f32_fp8(uC, 0);
            a1 += __builtin_amdgcn_cvt_f32_fp8(uD, 0);
            a2 += __builtin_amdgcn_cvt_f32_fp8(uE, 0);
            a3 += __builtin_amdgcn_cvt_f32_fp8(uF, 0);
        }
        // 8-wide tail
        for (; j + 8 <= end; j += 8) {
            int s0 = csr[j+0], s1 = csr[j+1], s2 = csr[j+2], s3 = csr[j+3];
            int s4 = csr[j+4], s5 = csr[j+5], s6 = csr[j+6], s7 = csr[j+7];
            unsigned w0_ = col[(size_t)s0 * HF], w1_ = col[(size_t)s1 * HF];
            unsigned w2_ = col[(size_t)s2 * HF], w3_ = col[(size_t)s3 * HF];
            unsigned w4_ = col[(size_t)s4 * HF], w5_ = col[(size_t)s5 * HF];
            unsigned w6_ = col[(size_t)s6 * HF], w7_ = col[(size_t)s7 * HF];
            a0 += __builtin_amdgcn_cvt_f32_fp8(w0_, 0);
            a1 += __builtin_amdgcn_cvt_f32_fp8(w1_, 0);
            a2 += __builtin_amdgcn_cvt_f32_fp8(w2_, 0);
            a3 += __builtin_amdgcn_cvt_f32_fp8(w3_, 0);
            a0 += __builtin_amdgcn_cvt_f32_fp8(w4_, 0);
            a1 += __builtin_amdgcn_cvt_f32_fp8(w5_, 0);
            a2 += __builtin_amdgcn_cvt_f32_fp8(w6_, 0);
            a3 += __builtin_amdgcn_cvt_f32_fp8(w7_, 0);
        }
        // scalar tail
        for (; j < end; ++j) {
            int s = csr[j];
            a0 += __builtin_amdgcn_cvt_f32_fp8((unsigned)col[(size_t)s * HF], 0);
        }

        float di = dinv[node];
        accP = ((a0 + a1) + (a2 + a3)) * di;
        diP = di;
        nodeP = node;
    }
    if (nodeP >= 0) mlp_store(accP, nodeP, diP);
}

// ---- per-graph mean-pool (bf16 input) + FC(64->32) relu + FC(32->2) sigmoid ----
__global__ void k_pool_fc(const unsigned short* __restrict__ h, const int* __restrict__ batch,
                          const float* __restrict__ Wf1, const float* __restrict__ bf1,
                          const float* __restrict__ Wf2, const float* __restrict__ bf2,
                          float* __restrict__ out, int N) {
    int g = blockIdx.x;
    int t = threadIdx.x;
    int f = t & 63, q = t >> 6;

    int lo = 0, hi = N;
    while (lo < hi) { int mid = (lo + hi) >> 1; if (batch[mid] < g) lo = mid + 1; else hi = mid; }
    int start = lo;
    hi = N;
    while (lo < hi) { int mid = (lo + hi) >> 1; if (batch[mid] < g + 1) lo = mid + 1; else hi = mid; }
    int end = lo;

    float sum = 0.f;
    for (int n = start + q; n < end; n += 4)
        sum += __uint_as_float(((unsigned)h[(size_t)n * HF + f]) << 16);

    __shared__ float red[4][HF];
    __shared__ float sp[HF];
    __shared__ float sh[32];
    red[q][f] = sum;
    __syncthreads();
    if (q == 0) {
        float s = red[0][f] + red[1][f] + red[2][f] + red[3][f];
        float cntf = (float)(end - start);
        sp[f] = s / fmaxf(cntf, 1.0f);
    }
    __syncthreads();
    if (t < 32) {
        float a = bf1[t];
#pragma unroll
        for (int k = 0; k < HF; ++k) a += sp[k] * Wf1[k * 32 + t];
        sh[t] = fmaxf(a, 0.f);
    }
    __syncthreads();
    if (t < 2) {
        float a = bf2[t];
#pragma unroll
        for (int k = 0; k < 32; ++k) a += sh[k] * Wf2[k * 2 + t];
        out[g * 2 + t] = 1.f / (1.f + expf(-a));
    }
}

extern "C" void kernel_launch(void* const* d_in, const int* in_sizes, int n_in,
                              void* d_out, int out_size, void* d_ws, size_t ws_size,
                              hipStream_t stream) {
    const float* x     = (const float*)d_in[0];
    const int*   ei    = (const int*)d_in[1];
    const int*   batch = (const int*)d_in[2];
    const float* W1 = (const float*)d_in[3];
    const float* b1 = (const float*)d_in[4];
    const float* g1 = (const float*)d_in[5];
    const float* be1 = (const float*)d_in[6];
    const float* rm1 = (const float*)d_in[7];
    const float* rv1 = (const float*)d_in[8];
    const float* W2 = (const float*)d_in[9];
    const float* b2 = (const float*)d_in[10];
    const float* g2 = (const float*)d_in[11];
    const float* be2 = (const float*)d_in[12];
    const float* rm2 = (const float*)d_in[13];
    const float* rv2 = (const float*)d_in[14];
    const float* W3 = (const float*)d_in[15];
    const float* b3 = (const float*)d_in[16];
    const float* g3 = (const float*)d_in[17];
    const float* be3 = (const float*)d_in[18];
    const float* rm3 = (const float*)d_in[19];
    const float* rv3 = (const float*)d_in[20];
    const float* Wf1 = (const float*)d_in[21];
    const float* bf1 = (const float*)d_in[22];
    const float* Wf2 = (const float*)d_in[23];
    const float* bf2 = (const float*)d_in[24];
    float* out = (float*)d_out;

    const int N = in_sizes[2];            // 100000
    const int E = in_sizes[1] / 2;        // 3200000
    const int G = out_size / 2;           // 256
    const int B = (N + BKN - 1) / BKN;    // buckets (196)

    char* ws = (char*)d_ws;
    size_t off = 0;
    auto alloc = [&](size_t bytes) {
        char* p = ws + off;
        off += (bytes + 255) & ~(size_t)255;
        return p;
    };
    const int nblk = (E + PB_TILE - 1) / PB_TILE;   // 391

    // H3 is bf16 now (N*HF*2); must still cover stage alias (E*4)
    size_t h3_bytes = (size_t)N * HF * 2;
    size_t st_bytes = (size_t)E * 4;
    unsigned short* H3 = (unsigned short*)alloc(h3_bytes > st_bytes ? h3_bytes : st_bytes);
    unsigned char* HS1      = (unsigned char*)alloc((size_t)N * HF);
    unsigned char* HS2      = (unsigned char*)alloc((size_t)N * HF);
    float*         xs       = (float*)alloc((size_t)N * 5 * sizeof(float) + 64);  // +pad
    float*         dinv     = (float*)alloc((size_t)N * sizeof(float));
    int*           base     = (int*)  alloc(((size_t)N + 1) * sizeof(int));
    int*           bcnt     = (int*)  alloc((size_t)NBUCK_MAX * sizeof(int));
    int*           bbase2   = (int*)  alloc(((size_t)NBUCK_MAX + 1) * sizeof(int));
    unsigned*      rtab     = (unsigned*)alloc((size_t)nblk * B * sizeof(unsigned));
    int*           csr      = (int*)  alloc((size_t)E * sizeof(int));
    int*           stage    = (int*)H3;   // alias: consumed (passC2) before H3 written (layer 3)

    const int* src = ei;
    const int* dst = ei + E;

    const int BT = 256;
    int gP  = (N * 5 + BT - 1) / BT;

    // ---- CSR build: in-tile binning + bucket atomics -> parallel scan -> scatter ----
    hipMemsetAsync(bcnt, 0, (size_t)B * sizeof(int), stream);
    k_passB2<<<nblk, PB_T, 0, stream>>>(src, dst, stage, rtab, bcnt, E, B);
    k_bscan3<<<1, 256, 0, stream>>>(bcnt, bbase2, base, B, N, E);
    k_passC2<<<B, 512, 0, stream>>>(stage, rtab, bbase2, base, dinv, csr, N, B, nblk);
    k_prescale<<<gP, BT, 0, stream>>>(x, dinv, xs, N * 5);

    // ---- fused layers (pipelined gathers; LDS weights; grid-stride over nodes) ----
    k_layer1<<<LGRID, BT, 0, stream>>>(xs, HS1, csr, base, dinv,
                                       W1, b1, g1, be1, rm1, rv1, N);
    k_layer<1><<<LGRID, BT, 0, stream>>>(HS1, HS2, csr, base, dinv,
                                         W2, b2, g2, be2, rm2, rv2, N);
    k_layer<0><<<LGRID, BT, 0, stream>>>(HS2, H3, csr, base, dinv,
                                         W3, b3, g3, be3, rm3, rv3, N);

    // ---- pool + MLP head ----
    k_pool_fc<<<G, BT, 0, stream>>>(H3, batch, Wf1, bf1, Wf2, bf2, out, N);
}

// Round 11
// 413.863 us; speedup vs baseline: 1.0517x; 1.0517x over previous
//
#include <hip/hip_runtime.h>
#include <hip/hip_bf16.h>

#define HF 64
#define EPS 1e-5f

#define BSH 9                    // bucket shift: 512 nodes / bucket
#define BKN (1 << BSH)           // 512 nodes per bucket
#define NBUCK_MAX 256            // >= ceil(N / BKN); also >= blockDim of scan kernels
#define PB_T 256                 // passB threads
#define PB_EPT 32                // edges per thread
#define PB_TILE (PB_T * PB_EPT)  // 8192 edges per block

#define LGRID 2048               // k_layer grid: grid-stride over nodes

typedef __hip_bfloat16 bf16;

__device__ __forceinline__ unsigned char f32_to_fp8(float v) {
    int p = __builtin_amdgcn_cvt_pk_fp8_f32(v, v, 0, false);
    return (unsigned char)(p & 0xff);
}

__device__ __forceinline__ float rdlane(float v, int k) {
    return __int_as_float(__builtin_amdgcn_readlane(__float_as_int(v), k));
}

__device__ __forceinline__ unsigned bf16_rne_hi(float x) {
    unsigned u = __float_as_uint(x);
    return (u + 0x7fffu + ((u >> 16) & 1u)) & 0xffff0000u;  // rounded, kept in high half
}

// ---- pass B2: bin each tile IN PLACE (block-local bucket sort) + run table ----
// stage[tile0..tile0+cnt) = tile's edges grouped by bucket; rtab[blk*B+b] = off<<14|cnt.
// Also accumulates global bucket totals bcnt via one atomic per (block,bucket).
__global__ __launch_bounds__(PB_T) void k_passB2(
    const int* __restrict__ src, const int* __restrict__ dst,
    int* __restrict__ stage, unsigned* __restrict__ rtab,
    int* __restrict__ bcnt, int E, int B) {
    __shared__ int scnt[NBUCK_MAX];
    __shared__ int sscan[PB_T];
    int t = threadIdx.x;
    int blk = blockIdx.x;
    int tile0 = blk * PB_TILE;

    for (int b = t; b < NBUCK_MAX; b += PB_T) scnt[b] = 0;
    __syncthreads();

    int rec[PB_EPT];
    int bkt[PB_EPT];
#pragma unroll
    for (int k = 0; k < PB_EPT; ++k) {
        int e = tile0 + k * PB_T + t;
        bkt[k] = -1;
        if (e < E) {
            int d = dst[e];
            int s = src[e];
            int b = d >> BSH;
            bkt[k] = b;
            rec[k] = s | ((d & (BKN - 1)) << 17);
            atomicAdd(&scnt[b], 1);
        }
    }
    __syncthreads();

    // exclusive scan of per-bucket counts (256-wide Hillis-Steele)
    int v = (t < B) ? scnt[t] : 0;
    sscan[t] = v;
    __syncthreads();
    for (int off = 1; off < PB_T; off <<= 1) {
        int val = sscan[t];
        int add = (t >= off) ? sscan[t - off] : 0;
        __syncthreads();
        sscan[t] = val + add;
        __syncthreads();
    }
    int excl = sscan[t] - v;
    if (t < B) {
        rtab[(size_t)blk * B + t] = ((unsigned)excl << 14) | (unsigned)v;
        scnt[t] = excl;     // reuse as write cursor
        if (v) atomicAdd(&bcnt[t], v);   // global bucket totals (cheap: 196 addrs)
    }
    __syncthreads();

#pragma unroll
    for (int k = 0; k < PB_EPT; ++k) {
        if (bkt[k] >= 0) {
            int loc = atomicAdd(&scnt[bkt[k]], 1);
            stage[tile0 + loc] = rec[k];   // block-private: stays in a 32KB window
        }
    }
}

// ---- bscan3: PARALLEL exclusive scan of bcnt (1 block, LDS Hillis-Steele) ----
__global__ void k_bscan3(const int* __restrict__ bcnt, int* __restrict__ bbase2,
                         int* __restrict__ base, int B, int N, int E) {
    __shared__ int tot[NBUCK_MAX];
    int t = threadIdx.x;   // blockDim == 256
    int v = (t < B) ? bcnt[t] : 0;
    tot[t] = v;
    __syncthreads();
    for (int off = 1; off < 256; off <<= 1) {
        int val = tot[t];
        int add = (t >= off) ? tot[t - off] : 0;
        __syncthreads();
        tot[t] = val + add;
        __syncthreads();
    }
    if (t < B) bbase2[t] = tot[t] - v;
    if (t == 0) { bbase2[B] = E; base[N] = E; }
}

// ---- pass C2: per bucket: walk runs -> LDS hist -> scan -> base/dinv/xs -> scatter ----
// Also folds the old k_prescale: thread t owns node n0+t and its dinv, so it
// writes xs[n] = x[n]*dinv inline (kills one kernel launch + one x pass).
__global__ __launch_bounds__(512) void k_passC2(const int* __restrict__ stage,
                                                const unsigned* __restrict__ rtab,
                                                const int* __restrict__ bb2,
                                                const float* __restrict__ x,
                                                int* __restrict__ base,
                                                float* __restrict__ dinv,
                                                float* __restrict__ xs,
                                                int* __restrict__ csr,
                                                int N, int B, int nblk) {
    __shared__ int lcnt[BKN];
    __shared__ int lscan[BKN];
    __shared__ int lcur[BKN];
    int beta = blockIdx.x;
    int n0 = beta * BKN;
    int n1 = n0 + BKN; if (n1 > N) n1 = N;
    int nn = n1 - n0;
    int t = threadIdx.x;       // blockDim == 512 == BKN
    int rg = t >> 4;           // run group 0..31 (32 runs in parallel)
    int le = t & 15;           // lane within run group
    lcnt[t] = 0;
    __syncthreads();

    // phase 1: histogram over this bucket's runs
    for (int blk0 = 0; blk0 < nblk; blk0 += 32) {
        int blk = blk0 + rg;
        if (blk < nblk) {
            unsigned rt = rtab[(size_t)blk * B + beta];
            int cnt = (int)(rt & 0x3FFFu);
            int off = blk * PB_TILE + (int)(rt >> 14);
            for (int i = le; i < cnt; i += 16)
                atomicAdd(&lcnt[stage[off + i] >> 17], 1);
        }
    }
    __syncthreads();
    int v = lcnt[t];
    lscan[t] = v;
    __syncthreads();
    for (int off = 1; off < 512; off <<= 1) {
        int val = lscan[t];
        int add = (t >= off) ? lscan[t - off] : 0;
        __syncthreads();
        lscan[t] = val + add;
        __syncthreads();
    }
    int b = bb2[beta] + lscan[t] - v;   // exclusive scan + bucket start
    if (t < nn) {
        int n = n0 + t;
        float di = rsqrtf((float)v + 1.0f);
        base[n] = b;
        dinv[n] = di;
#pragma unroll
        for (int c2 = 0; c2 < 5; ++c2)       // folded prescale
            xs[n * 5 + c2] = x[n * 5 + c2] * di;
    }
    lcur[t] = b;
    __syncthreads();

    // phase 2: scatter to csr
    for (int blk0 = 0; blk0 < nblk; blk0 += 32) {
        int blk = blk0 + rg;
        if (blk < nblk) {
            unsigned rt = rtab[(size_t)blk * B + beta];
            int cnt = (int)(rt & 0x3FFFu);
            int off = blk * PB_TILE + (int)(rt >> 14);
            for (int i = le; i < cnt; i += 16) {
                int r = stage[off + i];
                int pos = atomicAdd(&lcur[r >> 17], 1);
                csr[pos] = r & 0x1ffff;
            }
        }
    }
}

// ---- layer 1 fused: pipelined multi-neighbor gather (8 nbr / VMEM instr) ----
__global__ __launch_bounds__(256) void k_layer1(
    const float* __restrict__ xs, unsigned char* __restrict__ hout,
    const int* __restrict__ csr, const int* __restrict__ basep,
    const float* __restrict__ dinv,
    const float* __restrict__ W1, const float* __restrict__ b,
    const float* __restrict__ g, const float* __restrict__ be,
    const float* __restrict__ rm, const float* __restrict__ rv, int N) {
    __shared__ float sW[5 * HF];
    __shared__ float sB[HF];
    __shared__ float sScale[HF];
    if (threadIdx.x < HF) {
        int f = threadIdx.x;
        float scale = g[f] * rsqrtf(rv[f] + EPS);
        sScale[f] = scale;
        sB[f] = (b[f] - rm[f]) * scale + be[f];
    }
    __syncthreads();
    for (int i = threadIdx.x; i < 5 * HF; i += blockDim.x)
        sW[i] = W1[i] * sScale[i & (HF - 1)];
    __syncthreads();

    int lane = threadIdx.x & 63;
    int wave = threadIdx.x >> 6;
    int c  = lane & 7;     // feature (c<5 useful)
    int g8 = lane >> 3;    // neighbor slot 0..7
    int stride = gridDim.x * 4;

    auto mlp_store = [&](float accS, int nodeS, float diS) {
        float out = sB[lane];
#pragma unroll
        for (int k = 0; k < 5; ++k) out += __shfl(accS, k, 64) * sW[k * HF + lane];
        out = fmaxf(out, 0.f);
        hout[(size_t)nodeS * HF + lane] = f32_to_fp8(out * diS);
    };

    float accP = 0.f, diP = 0.f;
    int nodeP = -1;

    for (int node = blockIdx.x * 4 + wave; node < N; node += stride) {
        int j   = __builtin_amdgcn_readfirstlane(basep[node]);
        int end = __builtin_amdgcn_readfirstlane(basep[node + 1]);

        float a0 = 0.f, a1 = 0.f, a2 = 0.f, a3 = 0.f;
        if (g8 == 0 && c < 5) a0 = xs[node * 5 + c];   // self term, issued early

        // issue first 32-window before prev node's MLP
        float u0 = 0.f, u1 = 0.f, u2 = 0.f, u3 = 0.f;
        bool w0 = (j + 32 <= end);
        if (w0) {
            int s0 = csr[j + g8];
            int s1 = csr[j + 8 + g8];
            int s2 = csr[j + 16 + g8];
            int s3 = csr[j + 24 + g8];
            u0 = xs[s0 * 5 + c]; u1 = xs[s1 * 5 + c];
            u2 = xs[s2 * 5 + c]; u3 = xs[s3 * 5 + c];
        }

        if (nodeP >= 0) mlp_store(accP, nodeP, diP);   // LDS/VALU only

        if (w0) {
            j += 32;
            while (j + 32 <= end) {   // double-buffered: issue next, consume current
                int s0 = csr[j + g8];
                int s1 = csr[j + 8 + g8];
                int s2 = csr[j + 16 + g8];
                int s3 = csr[j + 24 + g8];
                float v0 = xs[s0 * 5 + c];
                float v1 = xs[s1 * 5 + c];
                float v2 = xs[s2 * 5 + c];
                float v3 = xs[s3 * 5 + c];
                a0 += u0; a1 += u1; a2 += u2; a3 += u3;
                u0 = v0; u1 = v1; u2 = v2; u3 = v3;
                j += 32;
            }
            a0 += u0; a1 += u1; a2 += u2; a3 += u3;
        }
        for (; j + 8 <= end; j += 8) {
            int s = csr[j + g8];
            a0 += xs[s * 5 + c];
        }
        if (j < end && j + g8 < end) {
            int s = csr[j + g8];
            a0 += xs[s * 5 + c];
        }

        // fold the 8 neighbor slots
        float acc = (a0 + a1) + (a2 + a3);
        acc += __shfl_xor(acc, 8, 64);
        acc += __shfl_xor(acc, 16, 64);
        acc += __shfl_xor(acc, 32, 64);

        float di = dinv[node];
        accP = acc * di;
        diP = di;
        nodeP = node;
    }
    if (nodeP >= 0) mlp_store(accP, nodeP, diP);
}

// ---- layers 2/3: round-8-proven pipelined byte-gather + LDS bf16 weights + readlane MLP ----
// (round-10's 16-wide windows + fdot2 regressed 84->90us: compiler wouldn't hold
//  32 live gather regs (VGPR stayed 36) and re-serialized the loads; cvt_pkrtz's
//  1-SGPR-per-VALU limit ate the dot2 savings. This is the measured-best config.)
// swp4 padded to [64][9] (stride 144B): conflict-free uint4 reads.
// SCALE_OUT=1: write fp8 hs=h*dinv. SCALE_OUT=0: write bf16 h (feeds pool).
template <int SCALE_OUT>
__global__ __launch_bounds__(256, 4) void k_layer(
    const unsigned char* __restrict__ hs8, void* __restrict__ hout_v,
    const int* __restrict__ csr, const int* __restrict__ basep,
    const float* __restrict__ dinv,
    const float* __restrict__ W, const float* __restrict__ b,
    const float* __restrict__ g, const float* __restrict__ be,
    const float* __restrict__ rm, const float* __restrict__ rv, int N) {
    __shared__ uint4 swp4[64][9];   // padded row: 144B stride, conflict-free reads

    int lane = threadIdx.x & 63;
    int wave = threadIdx.x >> 6;
    int stride = gridDim.x * 4;
    const unsigned char* col = hs8 + lane;   // lane's feature column

    // stage bf16-packed, BN-folded weight columns once per block
    if (threadIdx.x < 64) {
        int l = threadIdx.x;
        float sc = g[l] * rsqrtf(rv[l] + EPS);
#pragma unroll
        for (int c = 0; c < 8; ++c) {
            unsigned p[4];
#pragma unroll
            for (int q = 0; q < 4; ++q) {
                int k2 = c * 4 + q;
                unsigned lo = bf16_rne_hi(W[(2 * k2 + 0) * HF + l] * sc);
                unsigned hi = bf16_rne_hi(W[(2 * k2 + 1) * HF + l] * sc);
                p[q] = (lo >> 16) | hi;
            }
            swp4[l][c] = make_uint4(p[0], p[1], p[2], p[3]);
        }
    }
    __syncthreads();

    float scale = g[lane] * rsqrtf(rv[lane] + EPS);
    float bias  = (b[lane] - rm[lane]) * scale + be[lane];

    auto mlp_store = [&](float acc, int nodeS, float diS) {
        float o0 = bias, o1 = 0.f, o2 = 0.f, o3 = 0.f;
#pragma unroll
        for (int c = 0; c < 8; ++c) {
            uint4 pv = swp4[lane][c];
            int k0 = c * 8;
            o0 += rdlane(acc, k0 + 0) * __uint_as_float(pv.x << 16);
            o1 += rdlane(acc, k0 + 1) * __uint_as_float(pv.x & 0xffff0000u);
            o2 += rdlane(acc, k0 + 2) * __uint_as_float(pv.y << 16);
            o3 += rdlane(acc, k0 + 3) * __uint_as_float(pv.y & 0xffff0000u);
            o0 += rdlane(acc, k0 + 4) * __uint_as_float(pv.z << 16);
            o1 += rdlane(acc, k0 + 5) * __uint_as_float(pv.z & 0xffff0000u);
            o2 += rdlane(acc, k0 + 6) * __uint_as_float(pv.w << 16);
            o3 += rdlane(acc, k0 + 7) * __uint_as_float(pv.w & 0xffff0000u);
        }
        float out = fmaxf((o0 + o1) + (o2 + o3), 0.f);
        if (SCALE_OUT) {
            ((unsigned char*)hout_v)[(size_t)nodeS * HF + lane] = f32_to_fp8(out * diS);
        } else {
            ((unsigned short*)hout_v)[(size_t)nodeS * HF + lane] =
                (unsigned short)(bf16_rne_hi(out) >> 16);
        }
    };

    float accP = 0.f, diP = 0.f;
    int nodeP = -1;

    for (int node = blockIdx.x * 4 + wave; node < N; node += stride) {
        int j   = __builtin_amdgcn_readfirstlane(basep[node]);
        int end = __builtin_amdgcn_readfirstlane(basep[node + 1]);

        // self term (already *dinv[src])
        float a0 = __builtin_amdgcn_cvt_f32_fp8((unsigned)col[(size_t)node * HF], 0);
        float a1 = 0.f, a2 = 0.f, a3 = 0.f;

        // issue first 8-window BEFORE prev node's MLP -> loads fly under the MLP
        unsigned u0 = 0, u1 = 0, u2 = 0, u3 = 0, u4 = 0, u5 = 0, u6 = 0, u7 = 0;
        bool w0 = (j + 8 <= end);
        if (w0) {
            int s0 = csr[j+0], s1 = csr[j+1], s2 = csr[j+2], s3 = csr[j+3];
            int s4 = csr[j+4], s5 = csr[j+5], s6 = csr[j+6], s7 = csr[j+7];
            u0 = col[(size_t)s0 * HF]; u1 = col[(size_t)s1 * HF];
            u2 = col[(size_t)s2 * HF]; u3 = col[(size_t)s3 * HF];
            u4 = col[(size_t)s4 * HF]; u5 = col[(size_t)s5 * HF];
            u6 = col[(size_t)s6 * HF]; u7 = col[(size_t)s7 * HF];
        }

        // previous node's MLP + store (vmcnt-free: LDS + readlane + VALU only)
        if (nodeP >= 0) mlp_store(accP, nodeP, diP);

        if (w0) {
            j += 8;
            // steady state: issue window v while consuming window u (counted vmcnt)
            while (j + 8 <= end) {
                int t0 = csr[j+0], t1 = csr[j+1], t2 = csr[j+2], t3 = csr[j+3];
                int t4 = csr[j+4], t5 = csr[j+5], t6 = csr[j+6], t7 = csr[j+7];
                unsigned v0 = col[(size_t)t0 * HF];
                unsigned v1 = col[(size_t)t1 * HF];
                unsigned v2 = col[(size_t)t2 * HF];
                unsigned v3 = col[(size_t)t3 * HF];
                unsigned v4 = col[(size_t)t4 * HF];
                unsigned v5 = col[(size_t)t5 * HF];
                unsigned v6 = col[(size_t)t6 * HF];
                unsigned v7 = col[(size_t)t7 * HF];
                a0 += __builtin_amdgcn_cvt_f32_fp8(u0, 0);
                a1 += __builtin_amdgcn_cvt_f32_fp8(u1, 0);
                a2 += __builtin_amdgcn_cvt_f32_fp8(u2, 0);
                a3 += __builtin_amdgcn_cvt_f32_fp8(u3, 0);
                a0 += __builtin_amdgcn_cvt_f32_fp8(u4, 0);
                a1 += __builtin_amdgcn_cvt_f32_fp8(u5, 0);
                a2 += __builtin_amdgcn_cvt_f32_fp8(u6, 0);
                a3 += __builtin_amdgcn_cvt_f32_fp8(u7, 0);
                u0 = v0; u1 = v1; u2 = v2; u3 = v3;
                u4 = v4; u5 = v5; u6 = v6; u7 = v7;
                j += 8;
            }
            // drain final window
            a0 += __builtin_amdgcn_cvt_f32_fp8(u0, 0);
            a1 += __builtin_amdgcn_cvt_f32_fp8(u1, 0);
            a2 += __builtin_amdgcn_cvt_f32_fp8(u2, 0);
            a3 += __builtin_amdgcn_cvt_f32_fp8(u3, 0);
            a0 += __builtin_amdgcn_cvt_f32_fp8(u4, 0);
            a1 += __builtin_amdgcn_cvt_f32_fp8(u5, 0);
            a2 += __builtin_amdgcn_cvt_f32_fp8(u6, 0);
            a3 += __builtin_amdgcn_cvt_f32_fp8(u7, 0);
        }
        // tail < 8
        for (; j < end; ++j) {
            int s = csr[j];
            a0 += __builtin_amdgcn_cvt_f32_fp8((unsigned)col[(size_t)s * HF], 0);
        }

        float di = dinv[node];
        accP = ((a0 + a1) + (a2 + a3)) * di;
        diP = di;
        nodeP = node;
    }
    if (nodeP >= 0) mlp_store(accP, nodeP, diP);
}

// ---- per-graph mean-pool (bf16 input) + FC(64->32) relu + FC(32->2) sigmoid ----
__global__ void k_pool_fc(const unsigned short* __restrict__ h, const int* __restrict__ batch,
                          const float* __restrict__ Wf1, const float* __restrict__ bf1,
                          const float* __restrict__ Wf2, const float* __restrict__ bf2,
                          float* __restrict__ out, int N) {
    int g = blockIdx.x;
    int t = threadIdx.x;
    int f = t & 63, q = t >> 6;

    int lo = 0, hi = N;
    while (lo < hi) { int mid = (lo + hi) >> 1; if (batch[mid] < g) lo = mid + 1; else hi = mid; }
    int start = lo;
    hi = N;
    while (lo < hi) { int mid = (lo + hi) >> 1; if (batch[mid] < g + 1) lo = mid + 1; else hi = mid; }
    int end = lo;

    float sum = 0.f;
    for (int n = start + q; n < end; n += 4)
        sum += __uint_as_float(((unsigned)h[(size_t)n * HF + f]) << 16);

    __shared__ float red[4][HF];
    __shared__ float sp[HF];
    __shared__ float sh[32];
    red[q][f] = sum;
    __syncthreads();
    if (q == 0) {
        float s = red[0][f] + red[1][f] + red[2][f] + red[3][f];
        float cntf = (float)(end - start);
        sp[f] = s / fmaxf(cntf, 1.0f);
    }
    __syncthreads();
    if (t < 32) {
        float a = bf1[t];
#pragma unroll
        for (int k = 0; k < HF; ++k) a += sp[k] * Wf1[k * 32 + t];
        sh[t] = fmaxf(a, 0.f);
    }
    __syncthreads();
    if (t < 2) {
        float a = bf2[t];
#pragma unroll
        for (int k = 0; k < 32; ++k) a += sh[k] * Wf2[k * 2 + t];
        out[g * 2 + t] = 1.f / (1.f + expf(-a));
    }
}

extern "C" void kernel_launch(void* const* d_in, const int* in_sizes, int n_in,
                              void* d_out, int out_size, void* d_ws, size_t ws_size,
                              hipStream_t stream) {
    const float* x     = (const float*)d_in[0];
    const int*   ei    = (const int*)d_in[1];
    const int*   batch = (const int*)d_in[2];
    const float* W1 = (const float*)d_in[3];
    const float* b1 = (const float*)d_in[4];
    const float* g1 = (const float*)d_in[5];
    const float* be1 = (const float*)d_in[6];
    const float* rm1 = (const float*)d_in[7];
    const float* rv1 = (const float*)d_in[8];
    const float* W2 = (const float*)d_in[9];
    const float* b2 = (const float*)d_in[10];
    const float* g2 = (const float*)d_in[11];
    const float* be2 = (const float*)d_in[12];
    const float* rm2 = (const float*)d_in[13];
    const float* rv2 = (const float*)d_in[14];
    const float* W3 = (const float*)d_in[15];
    const float* b3 = (const float*)d_in[16];
    const float* g3 = (const float*)d_in[17];
    const float* be3 = (const float*)d_in[18];
    const float* rm3 = (const float*)d_in[19];
    const float* rv3 = (const float*)d_in[20];
    const float* Wf1 = (const float*)d_in[21];
    const float* bf1 = (const float*)d_in[22];
    const float* Wf2 = (const float*)d_in[23];
    const float* bf2 = (const float*)d_in[24];
    float* out = (float*)d_out;

    const int N = in_sizes[2];            // 100000
    const int E = in_sizes[1] / 2;        // 3200000
    const int G = out_size / 2;           // 256
    const int B = (N + BKN - 1) / BKN;    // buckets (196)

    char* ws = (char*)d_ws;
    size_t off = 0;
    auto alloc = [&](size_t bytes) {
        char* p = ws + off;
        off += (bytes + 255) & ~(size_t)255;
        return p;
    };
    const int nblk = (E + PB_TILE - 1) / PB_TILE;   // 391

    // H3 is bf16 (N*HF*2); buffer must still cover the stage alias (E*4)
    size_t h3_bytes = (size_t)N * HF * 2;
    size_t st_bytes = (size_t)E * 4;
    unsigned short* H3 = (unsigned short*)alloc(h3_bytes > st_bytes ? h3_bytes : st_bytes);
    unsigned char* HS1      = (unsigned char*)alloc((size_t)N * HF);
    unsigned char* HS2      = (unsigned char*)alloc((size_t)N * HF);
    float*         xs       = (float*)alloc((size_t)N * 5 * sizeof(float) + 64);  // +pad
    float*         dinv     = (float*)alloc((size_t)N * sizeof(float));
    int*           base     = (int*)  alloc(((size_t)N + 1) * sizeof(int));
    int*           bcnt     = (int*)  alloc((size_t)NBUCK_MAX * sizeof(int));
    int*           bbase2   = (int*)  alloc(((size_t)NBUCK_MAX + 1) * sizeof(int));
    unsigned*      rtab     = (unsigned*)alloc((size_t)nblk * B * sizeof(unsigned));
    int*           csr      = (int*)  alloc((size_t)E * sizeof(int));
    int*           stage    = (int*)H3;   // alias: consumed (passC2) before H3 written (layer 3)

    const int* src = ei;
    const int* dst = ei + E;

    const int BT = 256;

    // ---- CSR build: in-tile binning + bucket atomics -> parallel scan -> scatter ----
    // (passC2 also writes dinv and the prescaled xs — k_prescale is folded in.)
    hipMemsetAsync(bcnt, 0, (size_t)B * sizeof(int), stream);
    k_passB2<<<nblk, PB_T, 0, stream>>>(src, dst, stage, rtab, bcnt, E, B);
    k_bscan3<<<1, 256, 0, stream>>>(bcnt, bbase2, base, B, N, E);
    k_passC2<<<B, 512, 0, stream>>>(stage, rtab, bbase2, x, base, dinv, xs, csr, N, B, nblk);

    // ---- fused layers (pipelined gathers; LDS weights; grid-stride over nodes) ----
    k_layer1<<<LGRID, BT, 0, stream>>>(xs, HS1, csr, base, dinv,
                                       W1, b1, g1, be1, rm1, rv1, N);
    k_layer<1><<<LGRID, BT, 0, stream>>>(HS1, HS2, csr, base, dinv,
                                         W2, b2, g2, be2, rm2, rv2, N);
    k_layer<0><<<LGRID, BT, 0, stream>>>(HS2, H3, csr, base, dinv,
                                         W3, b3, g3, be3, rm3, rv3, N);

    // ---- pool + MLP head ----
    k_pool_fc<<<G, BT, 0, stream>>>(H3, batch, Wf1, bf1, Wf2, bf2, out, N);
}